// Round 15
// baseline (500.300 us; speedup 1.0000x reference)
//
#include <hip/hip_runtime.h>

typedef _Float16 h16;
typedef _Float16 half8 __attribute__((ext_vector_type(8)));
typedef float f32x4 __attribute__((ext_vector_type(4)));

#define EPS_RMS 1.1920929e-07f
#define MiB (1ull << 20)

// async global->LDS, 16B per lane (dest must be wave-uniform-base + lane*16)
__device__ __forceinline__ void gload_lds16(const void* g, void* l) {
  __builtin_amdgcn_global_load_lds(
      (const __attribute__((address_space(1))) unsigned int*)g,
      (__attribute__((address_space(3))) unsigned int*)l, 16, 0, 0);
}

// ---------------------------------------------------------------------------
// Generic MFMA GEMM core.  C[M,N] = A[M,K] @ B[K,N], B given as BT[N][K].
// SPLIT: fp16 hi/lo planes, compute hh + hl + lh.
// EPI: 0 f32; 1 f32+residual; 2 split fp16; 3 relu^2 fp16; 4 fp16.
// USECNT/GATHER: MoE ragged M + row gather.
// ASYNC: 0 reg-stage; 1 gload A+B prefetch dbuf; 2 A reg-prefetch + B gload.
// KS: K-split (pays only when it truly doubles blocks/CU — r13 lesson).
// SMALLM: 64-row A tile (waves 1x4, acc[4][2]) — doubles grid for fill-bound
//         shapes at zero extra partial traffic (r15; ASYNC=1 dense only).
// Fragment maps (16x16x32 f16): A/B elem j of lane l = T[l&15][8*(l>>4)+j];
// C/D: col=l&15, row=(l>>4)*4+j.
// ---------------------------------------------------------------------------
struct GemmP {
  const h16* Ah; const h16* Al;
  const h16* Bh; const h16* Bl;
  float* Cf; h16* Ch; h16* Cl;
  const float* R;
  const int* cnt; const int* off; const int* perm;
  long sAz, sBz, sCzHi, sCzLo;
  int M, N, K, lda, ldb, ldc;
  int zAoff, zBoff, zCoff, bzShift, czHiShift, czLoMask;
  float outScale;
};

template <int SPLIT, int EPI, int USECNT, int GATHER, int ASYNC, int KS, int SMALLM>
__global__ __launch_bounds__(256, 4) void gemm_k(GemmP p) {
  constexpr int NP = SPLIT ? 2 : 1;
  constexpr int NBUF = (ASYNC >= 1) ? 2 : 1;
  constexpr int AROWS = SMALLM ? 64 : 128;   // A tile rows
  constexpr int WC = SMALLM ? 4 : 2;         // waves along N
  constexpr int NI = SMALLM ? 2 : 4;         // 16-col frags per wave
  constexpr int APAD = (ASYNC == 1) ? 32 : 40;  // gload rows must be linear
  constexpr int BPAD = (ASYNC >= 1) ? 32 : 40;
  __shared__ __align__(16) h16 As[NBUF][NP][AROWS][APAD];
  __shared__ __align__(16) h16 Bs[NBUF][NP][128][BPAD];
  __shared__ int permLds[GATHER ? 128 : 1];

  // bijective 8-XCD swizzle of the flattened (bm,bn) index
  const int nwg = gridDim.x * gridDim.y;
  const int flat = blockIdx.y * gridDim.x + blockIdx.x;
  const int q8 = nwg >> 3, r8 = nwg & 7;
  const int xcd = flat & 7, sub = flat >> 3;
  const int swz = (xcd < r8 ? xcd * (q8 + 1) : r8 * (q8 + 1) + (xcd - r8) * q8) + sub;
  const int bm = swz % gridDim.x, bn = swz / gridDim.x;
  const int zl = blockIdx.z;

  int Meff, rowbase;
  if (USECNT) {
    Meff = p.cnt[zl]; rowbase = p.off[zl];
    if (bm * AROWS >= Meff) return;
  } else { Meff = p.M; rowbase = 0; }

  const int zA = zl + p.zAoff, zB = zl + p.zBoff, zC = zl + p.zCoff;
  const h16* Ah = p.Ah + (size_t)zA * p.sAz;
  const h16* Al = SPLIT ? p.Al + (size_t)zA * p.sAz : (const h16*)0;
  const size_t bofs = (size_t)(zB >> p.bzShift) * p.sBz;
  const h16* Bh = p.Bh + bofs;
  const h16* Bl = SPLIT ? p.Bl + bofs : (const h16*)0;
  const size_t cofs = (size_t)(zC >> p.czHiShift) * p.sCzHi +
                      (size_t)(zC & p.czLoMask) * p.sCzLo;

  const int tid = threadIdx.x;
  const int lane = tid & 63;
  const int wid = tid >> 6;
  const int wr = SMALLM ? 0 : (wid >> 1);
  const int wc = SMALLM ? wid : (wid & 1);
  const int fr = lane & 15, fq = lane >> 4;

  if (GATHER) {
    if (tid < 128) {
      const int local = bm * 128 + tid;
      permLds[tid] = (local < Meff) ? p.perm[rowbase + local] : -1;
    }
    __syncthreads();
  }

  const long arow0 = (long)rowbase + (long)bm * AROWS;  // contiguous-A base

  const f32x4 fz = {0.f, 0.f, 0.f, 0.f};
  f32x4 acc[4][NI];
#pragma unroll
  for (int m = 0; m < 4; ++m)
#pragma unroll
    for (int n = 0; n < NI; ++n) acc[m][n] = fz;

  const int nkt = p.K / 32;
  const int ktBeg = (KS > 1) ? zl * (nkt / KS) : 0;
  const int ktEnd = (KS > 1) ? ktBeg + nkt / KS : nkt;

  auto compute = [&](int buf) {
    half8 af[NP][4], bf[NP][NI];
#pragma unroll
    for (int m = 0; m < 4; ++m) {
      const int r = wr * 64 + m * 16 + fr;
      af[0][m] = *(const half8*)&As[buf][0][r][fq * 8];
      if (SPLIT) af[1][m] = *(const half8*)&As[buf][1][r][fq * 8];
    }
#pragma unroll
    for (int n = 0; n < NI; ++n) {
      const int c = wc * (16 * NI) + n * 16 + fr;
      bf[0][n] = *(const half8*)&Bs[buf][0][c][fq * 8];
      if (SPLIT) bf[1][n] = *(const half8*)&Bs[buf][1][c][fq * 8];
    }
#pragma unroll
    for (int m = 0; m < 4; ++m)
#pragma unroll
      for (int n = 0; n < NI; ++n) {
        acc[m][n] = __builtin_amdgcn_mfma_f32_16x16x32_f16(af[0][m], bf[0][n], acc[m][n], 0, 0, 0);
        if (SPLIT) {
          acc[m][n] = __builtin_amdgcn_mfma_f32_16x16x32_f16(af[0][m], bf[1][n], acc[m][n], 0, 0, 0);
          acc[m][n] = __builtin_amdgcn_mfma_f32_16x16x32_f16(af[1][m], bf[0][n], acc[m][n], 0, 0, 0);
        }
      }
  };

  if constexpr (ASYNC == 1) {
    auto stage = [&](int buf, int kt) {
      const int kb = kt * 32;
      // B tile: 128 rows x 32 k (two 16B chunks per thread per plane)
#pragma unroll
      for (int it = 0; it < 2; ++it) {
        const int d = (tid + it * 256) * 16;
        const int row = d >> 6;
        const int oct = (d >> 4) & 3;
        const size_t gb = ((size_t)(bn * 128 + row)) * p.ldb + kb + oct * 8;
        gload_lds16(Bh + gb, (char*)&Bs[buf][0][0][0] + d);
        if (SPLIT) gload_lds16(Bl + gb, (char*)&Bs[buf][1][0][0] + d);
      }
      // A tile: AROWS rows (1 or 2 chunks per thread per plane)
#pragma unroll
      for (int it = 0; it < AROWS / 64; ++it) {
        const int d = (tid + it * 256) * 16;
        const int row = d >> 6;
        const int oct = (d >> 4) & 3;
        const size_t ga = (size_t)(arow0 + row) * p.lda + kb + oct * 8;
        gload_lds16(Ah + ga, (char*)&As[buf][0][0][0] + d);
        if (SPLIT) gload_lds16(Al + ga, (char*)&As[buf][1][0][0] + d);
      }
    };
    stage(0, ktBeg);
    __syncthreads();
    int cur = 0;
    for (int kt = ktBeg; kt < ktEnd; ++kt) {
      if (kt + 1 < ktEnd) stage(cur ^ 1, kt + 1);  // prefetch flies during MFMA
      compute(cur);
      __syncthreads();
      cur ^= 1;
    }
  } else if constexpr (ASYNC == 2) {
    // A reg-prefetch (gather) + B gload dbuf; single barrier per K-tile.
    half8 aPre[2];
    auto loadA = [&](int kt) {
#pragma unroll
      for (int s = 0; s < 2; ++s) {
        const int seg = tid * 2 + s;
        const int row = seg >> 2, ks = (seg & 3) * 8;
        bool av; long arow;
        if (GATHER) { const int tk2 = permLds[row]; av = (tk2 >= 0); arow = tk2; }
        else { const int local = bm * 128 + row; av = (local < Meff); arow = (long)rowbase + local; }
        half8 v = {0,0,0,0,0,0,0,0};
        if (av) v = *(const half8*)(Ah + arow * (size_t)p.lda + kt * 32 + ks);
        aPre[s] = v;
      }
    };
    auto stageB2 = [&](int buf, int kt) {
      const int kb = kt * 32;
#pragma unroll
      for (int it = 0; it < 2; ++it) {
        const int d = (tid + it * 256) * 16;
        const int row = d >> 6;
        const int oct = (d >> 4) & 3;
        const size_t gb = ((size_t)(bn * 128 + row)) * p.ldb + kb + oct * 8;
        gload_lds16(Bh + gb, (char*)&Bs[buf][0][0][0] + d);
      }
    };
    loadA(ktBeg);
    stageB2(0, ktBeg);
    int cur = 0;
    for (int kt = ktBeg; kt < ktEnd; ++kt) {
#pragma unroll
      for (int s = 0; s < 2; ++s) {  // write prefetched A regs -> LDS
        const int seg = tid * 2 + s;
        const int row = seg >> 2, ks = (seg & 3) * 8;
        *(half8*)&As[cur][0][row][ks] = aPre[s];
      }
      __syncthreads();  // drains B gload(cur); syncs A writes
      if (kt + 1 < ktEnd) { loadA(kt + 1); stageB2(cur ^ 1, kt + 1); }
      compute(cur);
      cur ^= 1;
    }
  } else {
    for (int kt = ktBeg; kt < ktEnd; ++kt) {
      if (kt != ktBeg) __syncthreads();
      const int kb = kt * 32;
#pragma unroll
      for (int s = 0; s < 2; ++s) {
        const int seg = tid * 2 + s;  // 128 rows x 4 octets
        const int row = seg >> 2, ks = (seg & 3) * 8;
        const int local = bm * 128 + row;
        bool av; long arow;
        if (GATHER) { const int tk2 = permLds[row]; av = (tk2 >= 0); arow = tk2; }
        else { av = (local < Meff); arow = (long)rowbase + local; }
        half8 vh = {0,0,0,0,0,0,0,0}, vl = {0,0,0,0,0,0,0,0};
        if (av) {
          vh = *(const half8*)(Ah + arow * (size_t)p.lda + kb + ks);
          if (SPLIT) vl = *(const half8*)(Al + arow * (size_t)p.lda + kb + ks);
        }
        *(half8*)&As[0][0][row][ks] = vh;
        if (SPLIT) *(half8*)&As[0][1][row][ks] = vl;
        const long brow = (long)bn * 128 + row;
        *(half8*)&Bs[0][0][row][ks] = *(const half8*)(Bh + brow * (size_t)p.ldb + kb + ks);
        if (SPLIT)
          *(half8*)&Bs[0][1][row][ks] = *(const half8*)(Bl + brow * (size_t)p.ldb + kb + ks);
      }
      __syncthreads();
      compute(0);
    }
  }

#pragma unroll
  for (int m = 0; m < 4; ++m)
#pragma unroll
    for (int n = 0; n < NI; ++n)
#pragma unroll
      for (int j = 0; j < 4; ++j) {
        const int rl = wr * 64 + m * 16 + fq * 4 + j;
        const int cl = wc * (16 * NI) + n * 16 + fr;
        const int local = bm * AROWS + rl;
        if (local >= Meff) continue;
        const size_t idx = cofs + ((size_t)rowbase + local) * p.ldc + (size_t)bn * 128 + cl;
        const float v = acc[m][n][j] * p.outScale;
        if (EPI == 0) p.Cf[idx] = v;
        else if (EPI == 1) p.Cf[idx] = v + p.R[idx];
        else if (EPI == 2) {
          const h16 hh = (h16)v;
          p.Ch[idx] = hh; p.Cl[idx] = (h16)(v - (float)hh);
        } else if (EPI == 3) {
          const float r2 = v > 0.f ? v * v : 0.f;
          p.Ch[idx] = (h16)r2;
        } else {
          p.Ch[idx] = (h16)v;
        }
      }
}

// ---------------------------------------------------------------------------
// Flash attention, causal KV-split + T14 async-STAGE prefetch (round-9 form).
// ---------------------------------------------------------------------------
__global__ __launch_bounds__(512, 4) void flash_k(
    const h16* __restrict__ Qh, const h16* __restrict__ Ql,
    const h16* __restrict__ Kh, const h16* __restrict__ Kl,
    const h16* __restrict__ Vh, const h16* __restrict__ Vl,
    h16* __restrict__ yh, h16* __restrict__ yl,
    float* __restrict__ yp, float* __restrict__ mp, float* __restrict__ lp) {
  __shared__ __align__(16) h16 Ks[2][32][136];   // [plane][kv][d]  (B of QK^T)
  __shared__ __align__(16) h16 Vs[2][128][40];   // [plane][d][kv]  (B of PV)
  __shared__ __align__(16) h16 Ps[8][2][16][40]; // wave-private P transpose slab

  // heavy-first item table: {qb, chunk, isFull}
  const int QBT[12]  = {3, 7, 7, 6, 6, 2, 5, 5, 4, 4, 1, 0};
  const int CHT[12]  = {0, 0, 1, 0, 1, 0, 0, 1, 0, 1, 0, 0};
  const int FULT[12] = {1, 0, 0, 0, 0, 1, 0, 0, 0, 0, 1, 1};

  const int z = blockIdx.x, item = blockIdx.y;
  const int qb = QBT[item], chunk = CHT[item], full = FULT[item];
  const int nt = (qb + 1) * 4;
  const int tBeg = full ? 0 : (chunk ? nt / 2 : 0);
  const int tEnd = full ? nt : (chunk ? nt : nt / 2);

  const int b = z >> 4, h = z & 15;
  const size_t qoff = (size_t)z * 131072;
  const size_t koff = (size_t)(b * 4 + (h >> 2)) * 131072;

  const int tid = threadIdx.x;
  const int lane = tid & 63, w = tid >> 6;
  const int fr = lane & 15, fq = lane >> 4;

  // ---- Q fragments (persistent) ----
  const int qrow = qb * 128 + w * 16 + fr;
  half8 qa[2][4];
#pragma unroll
  for (int kt = 0; kt < 4; ++kt) {
    qa[0][kt] = *(const half8*)(Qh + qoff + (size_t)qrow * 128 + kt * 32 + fq * 8);
    qa[1][kt] = *(const half8*)(Ql + qoff + (size_t)qrow * 128 + kt * 32 + fq * 8);
  }

  const int kRow = tid >> 4, kSeg = tid & 15;   // K: 32 rows x 16 segs
  const int vRow = tid >> 2, vSeg = tid & 3;    // V: 128 rows x 4 segs

  half8 kreg[2], vreg[2];
  auto loadKV = [&](int t) {
    const int kvb = t * 32;
#pragma unroll
    for (int pl = 0; pl < 2; ++pl) {
      const h16* kp = pl ? Kl : Kh;
      const h16* vp = pl ? Vl : Vh;
      kreg[pl] = *(const half8*)(kp + koff + (size_t)(kvb + kRow) * 128 + kSeg * 8);
      vreg[pl] = *(const half8*)(vp + koff + (size_t)vRow * 1024 + kvb + vSeg * 8);
    }
  };

  const f32x4 fz = {0.f, 0.f, 0.f, 0.f};
  f32x4 y[8];
#pragma unroll
  for (int n = 0; n < 8; ++n) y[n] = fz;
  float mrow[4] = {-3.0e38f, -3.0e38f, -3.0e38f, -3.0e38f};
  float lrow[4] = {0.f, 0.f, 0.f, 0.f};

  loadKV(tBeg);
  for (int t = tBeg; t < tEnd; ++t) {
    const int kvb = t * 32;
    if (t != tBeg) __syncthreads();  // all waves done reading previous tile
#pragma unroll
    for (int pl = 0; pl < 2; ++pl) {
      *(half8*)&Ks[pl][kRow][kSeg * 8] = kreg[pl];
      *(half8*)&Vs[pl][vRow][vSeg * 8] = vreg[pl];
    }
    __syncthreads();
    if (t + 1 < tEnd) loadKV(t + 1);  // next tile's loads fly under compute

    // ---- S = Q @ K^T ----
    f32x4 sf[2] = {fz, fz};
#pragma unroll
    for (int n = 0; n < 2; ++n)
#pragma unroll
      for (int kt = 0; kt < 4; ++kt) {
        const half8 bh2 = *(const half8*)&Ks[0][n * 16 + fr][kt * 32 + fq * 8];
        const half8 bl2 = *(const half8*)&Ks[1][n * 16 + fr][kt * 32 + fq * 8];
        sf[n] = __builtin_amdgcn_mfma_f32_16x16x32_f16(qa[0][kt], bh2, sf[n], 0, 0, 0);
        sf[n] = __builtin_amdgcn_mfma_f32_16x16x32_f16(qa[0][kt], bl2, sf[n], 0, 0, 0);
        sf[n] = __builtin_amdgcn_mfma_f32_16x16x32_f16(qa[1][kt], bh2, sf[n], 0, 0, 0);
      }

    if (kvb + 31 > qb * 128) {
#pragma unroll
      for (int n = 0; n < 2; ++n)
#pragma unroll
        for (int j = 0; j < 4; ++j) {
          const int kvg = kvb + n * 16 + fr;
          const int qg = qb * 128 + w * 16 + fq * 4 + j;
          if (kvg > qg) sf[n][j] = -3.0e38f;
        }
    }

    float al[4];
#pragma unroll
    for (int j = 0; j < 4; ++j) {
      float tm = fmaxf(sf[0][j], sf[1][j]);
#pragma unroll
      for (int msk = 1; msk < 16; msk <<= 1) tm = fmaxf(tm, __shfl_xor(tm, msk, 16));
      const float mn = fmaxf(mrow[j], tm);
      al[j] = __expf(mrow[j] - mn);
      mrow[j] = mn;
      sf[0][j] = __expf(sf[0][j] - mn);
      sf[1][j] = __expf(sf[1][j] - mn);
      float ts = sf[0][j] + sf[1][j];
#pragma unroll
      for (int msk = 1; msk < 16; msk <<= 1) ts += __shfl_xor(ts, msk, 16);
      lrow[j] = lrow[j] * al[j] + ts;
    }
#pragma unroll
    for (int n = 0; n < 8; ++n)
#pragma unroll
      for (int j = 0; j < 4; ++j) y[n][j] *= al[j];

#pragma unroll
    for (int n = 0; n < 2; ++n)
#pragma unroll
      for (int j = 0; j < 4; ++j) {
        const float pp = sf[n][j] * 1024.f;
        const h16 hh = (h16)pp;
        Ps[w][0][fq * 4 + j][n * 16 + fr] = hh;
        Ps[w][1][fq * 4 + j][n * 16 + fr] = (h16)(pp - (float)hh);
      }

    const half8 pah = *(const half8*)&Ps[w][0][fr][fq * 8];
    const half8 pal = *(const half8*)&Ps[w][1][fr][fq * 8];
#pragma unroll
    for (int n = 0; n < 8; ++n) {
      const half8 vh2 = *(const half8*)&Vs[0][n * 16 + fr][fq * 8];
      const half8 vl2 = *(const half8*)&Vs[1][n * 16 + fr][fq * 8];
      y[n] = __builtin_amdgcn_mfma_f32_16x16x32_f16(pah, vh2, y[n], 0, 0, 0);
      y[n] = __builtin_amdgcn_mfma_f32_16x16x32_f16(pah, vl2, y[n], 0, 0, 0);
      y[n] = __builtin_amdgcn_mfma_f32_16x16x32_f16(pal, vh2, y[n], 0, 0, 0);
    }
  }

  if (full) {
#pragma unroll
    for (int n = 0; n < 8; ++n)
#pragma unroll
      for (int j = 0; j < 4; ++j) {
        const int row = qb * 128 + w * 16 + fq * 4 + j;
        const int col = h * 128 + n * 16 + fr;
        const float v = y[n][j] / (1024.f * lrow[j]);
        const size_t idx = ((size_t)(b * 1024 + row)) * 2048 + col;
        const h16 hh = (h16)v;
        yh[idx] = hh; yl[idx] = (h16)(v - (float)hh);
      }
  } else {
#pragma unroll
    for (int j = 0; j < 4; ++j) {
      const int qrl = w * 16 + fq * 4 + j;              // 0..127 local row
      const int q512 = (qb - 4) * 128 + qrl;            // 0..511
      const size_t rbase = (((size_t)chunk * 32 + z) * 512 + q512);
#pragma unroll
      for (int n = 0; n < 8; ++n)
        yp[rbase * 128 + n * 16 + fr] = y[n][j];
      if (fr == 0) { mp[rbase] = mrow[j]; lp[rbase] = lrow[j]; }
    }
  }
}

// ---------------------------------------------------------------------------
// Merge the two KV-chunk partials for qb in [4,8).  float4-vectorized.
// ---------------------------------------------------------------------------
__global__ void comb_k(const float* __restrict__ yp, const float* __restrict__ mp,
                       const float* __restrict__ lp,
                       h16* __restrict__ yh, h16* __restrict__ yl) {
  const int qh = blockIdx.x, z = blockIdx.y;
  const int b = z >> 4, h = z & 15;
  const int tid = threadIdx.x;
  for (int i4 = tid; i4 < 4096; i4 += 256) {   // 128 rows x 32 float4
    const int r = i4 >> 5, d4 = (i4 & 31) * 4;
    const int q512 = qh * 128 + r;
    const size_t r0 = ((size_t)0 * 32 + z) * 512 + q512;
    const size_t r1 = ((size_t)1 * 32 + z) * 512 + q512;
    const float m1 = mp[r0], m2 = mp[r1];
    const float l1 = lp[r0], l2 = lp[r1];
    const float M = fmaxf(m1, m2);
    const float e1 = __expf(m1 - M), e2 = __expf(m2 - M);
    const float inv = 1.f / (1024.f * (l1 * e1 + l2 * e2));
    const f32x4 a = *(const f32x4*)(yp + r0 * 128 + d4);
    const f32x4 c = *(const f32x4*)(yp + r1 * 128 + d4);
    const size_t o = ((size_t)(b * 1024 + (4 + qh) * 128 + r)) * 2048 + h * 128 + d4;
#pragma unroll
    for (int j = 0; j < 4; ++j) {
      const float v = (a[j] * e1 + c[j] * e2) * inv;
      const h16 hh = (h16)v;
      yh[o + j] = hh; yl[o + j] = (h16)(v - (float)hh);
    }
  }
}

// ---------------------------------------------------------------------------
// Weight transpose + fp16 hi/lo split, vectorized half8 stores.
// ---------------------------------------------------------------------------
__global__ void tsplit_k(const float* __restrict__ W, h16* __restrict__ Th,
                         h16* __restrict__ Tl, int K, int N, float scale, int wantLo) {
  const size_t eoff = (size_t)blockIdx.z * (size_t)K * N;
  W += eoff; Th += eoff; if (Tl) Tl += eoff;
  __shared__ float tile[32][33];
  const int nt = blockIdx.x * 32, kt = blockIdx.y * 32;
  const int c = threadIdx.x & 31, r0 = threadIdx.x >> 5;
#pragma unroll
  for (int rr = 0; rr < 4; ++rr)
    tile[r0 + rr * 8][c] = W[(size_t)(kt + r0 + rr * 8) * N + nt + c];
  __syncthreads();
  const int t = threadIdx.x;
  const int pl = t >> 7;                       // 0 = hi, 1 = lo
  if (pl == 1 && !wantLo) return;
  const int n = (t & 127) >> 2, ks = (t & 3) * 8;
  half8 o;
#pragma unroll
  for (int i = 0; i < 8; ++i) {
    const float v = tile[ks + i][n] * scale;
    const h16 hh = (h16)v;
    o[i] = pl ? (h16)(v - (float)hh) : hh;
  }
  h16* dst = pl ? Tl : Th;
  *(half8*)&dst[(size_t)(nt + n) * K + kt + ks] = o;
}

// ---------------------------------------------------------------------------
// Row RMS-norm (C=2048) -> fp16 hi (+optional lo)
// ---------------------------------------------------------------------------
template <int WLO>
__global__ void rms_k(const float* __restrict__ X, h16* __restrict__ H,
                      h16* __restrict__ L) {
  const int row = blockIdx.x;
  const float* x = X + (size_t)row * 2048;
  __shared__ float red[256];
  const int tid = threadIdx.x;
  float ss = 0.f;
  for (int c = tid; c < 2048; c += 256) { const float v = x[c]; ss += v * v; }
  red[tid] = ss; __syncthreads();
  for (int t = 128; t > 0; t >>= 1) {
    if (tid < t) red[tid] += red[tid + t];
    __syncthreads();
  }
  const float sc = rsqrtf(red[0] * (1.f / 2048.f) + EPS_RMS);
  for (int c = tid; c < 2048; c += 256) {
    const float v = x[c] * sc;
    const size_t o2 = (size_t)row * 2048 + c;
    const h16 hh = (h16)v;
    H[o2] = hh;
    if (WLO) L[o2] = (h16)(v - (float)hh);
  }
}

// ---------------------------------------------------------------------------
// Fused: x2 = x + P0 + P1 (Wo split-K partials), rms(x2) -> xfh, router.
// float4 contiguous loads (16B/lane); row segment of 8 cols per thread.
// ---------------------------------------------------------------------------
__global__ void rmsrouter_k(const float* __restrict__ x, const float* __restrict__ P0,
                            const float* __restrict__ P1, const float* __restrict__ Wr,
                            float* __restrict__ x2, h16* __restrict__ xfh,
                            int* __restrict__ idx2, float* __restrict__ g2,
                            int* __restrict__ cnt) {
  const int n = blockIdx.x, tid = threadIdx.x;
  __shared__ float redss[256];
  __shared__ float red8[256][8];
  const size_t rb = (size_t)n * 2048;
  const int c0 = tid * 8;
  float vreg[8];
  float ss = 0.f;
  float part[8] = {0, 0, 0, 0, 0, 0, 0, 0};
#pragma unroll
  for (int h = 0; h < 2; ++h) {
    const size_t o = rb + c0 + h * 4;
    const f32x4 a = *(const f32x4*)(x + o);
    const f32x4 b = *(const f32x4*)(P0 + o);
    const f32x4 c = *(const f32x4*)(P1 + o);
    f32x4 v;
#pragma unroll
    for (int j = 0; j < 4; ++j) {
      v[j] = a[j] + b[j] + c[j];
      vreg[h * 4 + j] = v[j];
      ss += v[j] * v[j];
      const float* w2 = Wr + (size_t)(c0 + h * 4 + j) * 8;
#pragma unroll
      for (int e = 0; e < 8; ++e) part[e] += v[j] * w2[e];
    }
    *(f32x4*)(x2 + o) = v;
  }
  redss[tid] = ss;
#pragma unroll
  for (int e = 0; e < 8; ++e) red8[tid][e] = part[e];
  __syncthreads();
  for (int t = 128; t > 0; t >>= 1) {
    if (tid < t) {
      redss[tid] += redss[tid + t];
#pragma unroll
      for (int e = 0; e < 8; ++e) red8[tid][e] += red8[tid + t][e];
    }
    __syncthreads();
  }
  const float sc = rsqrtf(redss[0] * (1.f / 2048.f) + EPS_RMS);
  half8 xo;
#pragma unroll
  for (int i = 0; i < 8; ++i) xo[i] = (h16)(vreg[i] * sc);
  *(half8*)&xfh[rb + c0] = xo;
  if (tid == 0) {
    float l[8];
#pragma unroll
    for (int e = 0; e < 8; ++e) l[e] = red8[0][e] * sc;
    int i1 = 0;
    for (int e = 1; e < 8; ++e) if (l[e] > l[i1]) i1 = e;
    int i2 = (i1 == 0) ? 1 : 0;
    for (int e = 0; e < 8; ++e) if (e != i1 && l[e] > l[i2]) i2 = e;
    const float e2 = __expf(l[i2] - l[i1]);
    const float inv = 1.f / (1.f + e2);
    idx2[n * 2] = i1; idx2[n * 2 + 1] = i2;
    g2[n * 2] = inv; g2[n * 2 + 1] = e2 * inv;
    atomicAdd(&cnt[i1], 1); atomicAdd(&cnt[i2], 1);
  }
}

// ---------------------------------------------------------------------------
// RoPE + per-head RMS on q/k, split fp16; V stored transposed [z][d][t].
// ---------------------------------------------------------------------------
__global__ void rope_k(const float* __restrict__ qkv, const float* __restrict__ cosT,
                       const float* __restrict__ sinT,
                       h16* __restrict__ Qh, h16* __restrict__ Ql,
                       h16* __restrict__ Kh, h16* __restrict__ Kl,
                       h16* __restrict__ Vh, h16* __restrict__ Vl) {
  const int tok = blockIdx.x;
  const int b = tok >> 10, t = tok & 1023;
  const int u = blockIdx.y, d = threadIdx.x;
  __shared__ float buf[128];
  __shared__ float red[128];
  int col;
  if (u < 16) col = u * 128 + d;
  else if (u < 20) col = 2048 + (u - 16) * 128 + d;
  else col = 2560 + (u - 20) * 128 + d;
  float v = qkv[(size_t)tok * 3072 + col];
  if (u < 20) {
    buf[d] = v; __syncthreads();
    float r;
    if (d < 64) {
      const float c = cosT[t * 64 + d], s = sinT[t * 64 + d];
      r = buf[d] * c + buf[d + 64] * s;
    } else {
      const float c = cosT[t * 64 + d - 64], s = sinT[t * 64 + d - 64];
      r = -buf[d - 64] * s + buf[d] * c;
    }
    red[d] = r * r; __syncthreads();
    for (int tt = 64; tt > 0; tt >>= 1) {
      if (d < tt) red[d] += red[d + tt];
      __syncthreads();
    }
    v = r * rsqrtf(red[0] * (1.f / 128.f) + EPS_RMS);
    if (u < 16) v *= 0.08838834764831845f;  // 1/sqrt(128)
  }
  const h16 hh = (h16)v;
  const h16 lo = (h16)(v - (float)hh);
  if (u < 16) {
    const size_t o2 = (((size_t)(b * 16 + u)) * 1024 + t) * 128 + d;
    Qh[o2] = hh; Ql[o2] = lo;
  } else if (u < 20) {
    const size_t o2 = (((size_t)(b * 4 + (u - 16))) * 1024 + t) * 128 + d;
    Kh[o2] = hh; Kl[o2] = lo;
  } else {
    const size_t o2 = ((size_t)(b * 4 + (u - 20))) * 131072 + (size_t)d * 1024 + t;
    Vh[o2] = hh; Vl[o2] = lo;
  }
}

__global__ void zero8_k(int* __restrict__ p) {
  if (threadIdx.x < 16 && blockIdx.x == 0) p[threadIdx.x] = 0;
}

// scan + virtual dense expert 8 (cnt=2048, off=4096) for the fused MoE GEMMs
__global__ void scan_k(int* __restrict__ cnt, int* __restrict__ off,
                       int* __restrict__ base) {
  if (threadIdx.x == 0 && blockIdx.x == 0) {
    int a = 0;
    for (int e = 0; e < 8; ++e) { off[e] = a; base[e] = a; a += cnt[e]; }
    off[8] = a; base[8] = a; cnt[8] = 2048;  // a == 4096 (2 experts/token)
  }
}

// assign + identity perm for the virtual dense expert
__global__ void assign_k(const int* __restrict__ idx2, int* __restrict__ base,
                         int* __restrict__ perm, int* __restrict__ pos2) {
  const int n = blockIdx.x * 256 + threadIdx.x;
  if (n >= 2048) return;
  perm[4096 + n] = n;
  for (int j = 0; j < 2; ++j) {
    const int e = idx2[n * 2 + j];
    const int pos = atomicAdd(&base[e], 1);
    perm[pos] = n;
    pos2[n * 2 + j] = pos;
  }
}

// out = x2 + shared(rpx rows 4096+) + gated routed; half8/float4 vectorized.
__global__ void combine_k(const float* __restrict__ x2, const h16* __restrict__ rpx,
                          const int* __restrict__ pos2,
                          const float* __restrict__ g2, float* __restrict__ out) {
  const int n = blockIdx.x;
  const int p0 = pos2[n * 2], p1 = pos2[n * 2 + 1];
  const float g0 = g2[n * 2], g1 = g2[n * 2 + 1];
  const int c0 = threadIdx.x * 8;
  const size_t i0 = (size_t)n * 2048 + c0;
  const half8 shv = *(const half8*)(rpx + (size_t)(4096 + n) * 2048 + c0);
  const half8 r0v = *(const half8*)(rpx + (size_t)p0 * 2048 + c0);
  const half8 r1v = *(const half8*)(rpx + (size_t)p1 * 2048 + c0);
#pragma unroll
  for (int h = 0; h < 2; ++h) {
    const f32x4 xa = *(const f32x4*)(x2 + i0 + h * 4);
    f32x4 o;
#pragma unroll
    for (int j = 0; j < 4; ++j) {
      const int k = h * 4 + j;
      o[j] = xa[j] + (float)shv[k] + g0 * (float)r0v[k] + g1 * (float)r1v[k];
    }
    *(f32x4*)(out + i0 + h * 4) = o;
  }
}

// ---------------------------------------------------------------------------
extern "C" void kernel_launch(void* const* d_in, const int* in_sizes, int n_in,
                              void* d_out, int out_size, void* d_ws, size_t ws_size,
                              hipStream_t stream) {
  const float* x    = (const float*)d_in[0];
  const float* cosT = (const float*)d_in[1];
  const float* sinT = (const float*)d_in[2];
  const float* Wq   = (const float*)d_in[3];
  const float* Wk   = (const float*)d_in[4];
  const float* Wv   = (const float*)d_in[5];
  const float* Wo   = (const float*)d_in[6];
  const float* Wr   = (const float*)d_in[7];
  const float* Ws1  = (const float*)d_in[8];
  const float* Ws2  = (const float*)d_in[9];
  const float* We1  = (const float*)d_in[10];
  const float* We2  = (const float*)d_in[11];
  float* out = (float*)d_out;

  // -------- fixed 123 MiB workspace layout (lifetime-overlapped regions) ----
  unsigned char* W = (unsigned char*)d_ws;
  int*   idx2 = (int*)(W + 0);              // 16KB
  float* g2   = (float*)(W + 16 * 1024);    // 16KB
  int*   cnt  = (int*)(W + 32 * 1024);
  int*   offs = (int*)(W + 33 * 1024);
  int*   base = (int*)(W + 34 * 1024);
  int*   pos2 = (int*)(W + 36 * 1024);      // 16KB
  int*   perm = (int*)(W + 56 * 1024);      // 24KB (6144 ints)
  // R1 [1,25): W1 (Wqkv split) -> W2 (Wo split)
  h16* W1h = (h16*)(W + 1 * MiB);
  h16* W1l = (h16*)(W + 13 * MiB);
  h16* W2h = (h16*)(W + 1 * MiB);
  h16* W2l = (h16*)(W + 9 * MiB);
  // R2 [25,41): xn -> y -> xf
  h16* xnh = (h16*)(W + 25 * MiB);
  h16* xnl = (h16*)(W + 33 * MiB);
  h16* yh  = (h16*)(W + 25 * MiB);
  h16* yl  = (h16*)(W + 33 * MiB);
  h16* xfh = (h16*)(W + 25 * MiB);
  // R3 [41,65): qkv f32 (24 MiB) -> flash partials -> Wo partials -> hcomb
  float* qkv = (float*)(W + 41 * MiB);
  float* ypart = (float*)(W + 41 * MiB);   // 16 MiB: [2][32][512][128] f32
  float* mpart = (float*)(W + 57 * MiB);
  float* lpart = (float*)(W + 58 * MiB);
  float* wopart = (float*)(W + 41 * MiB);  // 2 x 16 MiB f32 planes (41,57)
  h16* hcomb = (h16*)(W + 41 * MiB);       // 6144x512 h16 (6 MiB)
  // R4 [65,89): Q/K/V split -> rpx (6144x2048 h16, 24MiB)
  h16* Qh = (h16*)(W + 65 * MiB);
  h16* Ql = (h16*)(W + 73 * MiB);
  h16* Kh = (h16*)(W + 81 * MiB);
  h16* Kl = (h16*)(W + 83 * MiB);
  h16* Vh = (h16*)(W + 85 * MiB);
  h16* Vl = (h16*)(W + 87 * MiB);
  h16* rpx = (h16*)(W + 65 * MiB);
  // R5 [89,105): x2 f32
  float* x2 = (float*)(W + 89 * MiB);
  // R6 [105,123): MoE weights, 9 planes x 2MiB (plane 8 = shared expert)
  h16* WeT = (h16*)(W + 105 * MiB);
  h16* WsPlane8 = WeT + (size_t)8 * 1048576;

  const float WS = 64.f;
  const float IWS = 1.f / 64.f;

  // ---- phase 1: Wqkv prep, rms(x), qkv GEMM (64-row tiles, 768 blocks) ----
  tsplit_k<<<dim3(64, 64, 1), 256, 0, stream>>>(Wq, W1h, W1l, 2048, 2048, WS, 1);
  tsplit_k<<<dim3(16, 64, 1), 256, 0, stream>>>(Wk, W1h + (size_t)2048 * 2048,
                                                W1l + (size_t)2048 * 2048, 2048, 512, WS, 1);
  tsplit_k<<<dim3(16, 64, 1), 256, 0, stream>>>(Wv, W1h + (size_t)2560 * 2048,
                                                W1l + (size_t)2560 * 2048, 2048, 512, WS, 1);
  zero8_k<<<1, 64, 0, stream>>>(cnt);
  rms_k<1><<<2048, 256, 0, stream>>>(x, xnh, xnl);
  {
    GemmP p{};
    p.Ah = xnh; p.Al = xnl; p.Bh = W1h; p.Bl = W1l; p.Cf = qkv;
    p.M = 2048; p.N = 3072; p.K = 2048; p.lda = 2048; p.ldb = 2048; p.ldc = 3072;
    p.outScale = IWS;
    gemm_k<1, 0, 0, 0, 1, 1, 1><<<dim3(32, 24, 1), 256, 0, stream>>>(p);
  }

  // ---- phase 2: rope + head-rms (qkv dead after) ----
  rope_k<<<dim3(2048, 24, 1), 128, 0, stream>>>(qkv, cosT, sinT, Qh, Ql, Kh, Kl, Vh, Vl);

  // ---- phase 3: Wo prep + flash attention (KV-split, heavy-first) + merge --
  tsplit_k<<<dim3(64, 64, 1), 256, 0, stream>>>(Wo, W2h, W2l, 2048, 2048, WS, 1);
  flash_k<<<dim3(32, 12, 1), 512, 0, stream>>>(Qh, Ql, Kh, Kl, Vh, Vl, yh, yl,
                                               ypart, mpart, lpart);
  comb_k<<<dim3(4, 32, 1), 256, 0, stream>>>(ypart, mpart, lpart, yh, yl);

  // ---- phase 4: Wo split-K x2 -> f32 partials (sum fused into rmsrouter) ---
  {
    GemmP p{};
    p.Ah = yh; p.Al = yl; p.Bh = W2h; p.Bl = W2l; p.Cf = wopart;
    p.M = 2048; p.N = 2048; p.K = 2048; p.lda = 2048; p.ldb = 2048; p.ldc = 2048;
    p.sCzHi = (long)2048 * 2048;  // partial plane stride (16 MiB)
    p.outScale = IWS;
    gemm_k<1, 0, 0, 0, 1, 2, 0><<<dim3(16, 16, 2), 256, 0, stream>>>(p);
  }

  // ---- phase 5: fused x2-sum + rms + router; scan+assign ----
  rmsrouter_k<<<2048, 256, 0, stream>>>(x, wopart, wopart + (size_t)2048 * 2048,
                                        Wr, x2, xfh, idx2, g2, cnt);
  scan_k<<<1, 64, 0, stream>>>(cnt, offs, base);
  assign_k<<<8, 256, 0, stream>>>(idx2, base, perm, pos2);

  // ---- phase 6: MoE, horizontally fused (8 experts + shared as plane 8) ----
  tsplit_k<<<dim3(16, 64, 8), 256, 0, stream>>>(We1, WeT, (h16*)0, 2048, 512, WS, 0);
  tsplit_k<<<dim3(16, 64, 1), 256, 0, stream>>>(Ws1, WsPlane8, (h16*)0, 2048, 512, WS, 0);
  {
    GemmP p{};  // hcomb = relu(gather(xf) @ We1[z])^2, z=8 -> shared (identity)
    p.Ah = xfh; p.Bh = WeT; p.Ch = hcomb;
    p.N = 512; p.K = 2048; p.lda = 2048; p.ldb = 2048; p.ldc = 512;
    p.sBz = (long)512 * 2048; p.bzShift = 0;
    p.cnt = cnt; p.off = offs; p.perm = perm;
    p.outScale = IWS;
    gemm_k<0, 3, 1, 1, 2, 1, 0><<<dim3(16, 4, 9), 256, 0, stream>>>(p);
  }
  tsplit_k<<<dim3(64, 16, 8), 256, 0, stream>>>(We2, WeT, (h16*)0, 512, 2048, WS, 0);
  tsplit_k<<<dim3(64, 16, 1), 256, 0, stream>>>(Ws2, WsPlane8, (h16*)0, 512, 2048, WS, 0);
  {
    GemmP p{};  // rpx = hcomb @ We2[z] (contiguous A rows, full async dbuf)
    p.Ah = hcomb; p.Bh = WeT; p.Ch = rpx;
    p.N = 2048; p.K = 512; p.lda = 512; p.ldb = 512; p.ldc = 2048;
    p.sBz = (long)2048 * 512; p.bzShift = 0;
    p.cnt = cnt; p.off = offs; p.perm = perm;
    p.outScale = IWS;
    gemm_k<0, 4, 1, 0, 1, 1, 0><<<dim3(16, 16, 9), 256, 0, stream>>>(p);
  }

  // ---- phase 7: out = x2 + shared + gated routed ----
  combine_k<<<2048, 256, 0, stream>>>(x2, rpx, pos2, g2, out);
}

// Round 16
// 485.957 us; speedup vs baseline: 1.0295x; 1.0295x over previous
//
#include <hip/hip_runtime.h>

typedef _Float16 h16;
typedef _Float16 half8 __attribute__((ext_vector_type(8)));
typedef float f32x4 __attribute__((ext_vector_type(4)));

#define EPS_RMS 1.1920929e-07f
#define MiB (1ull << 20)

// async global->LDS, 16B per lane (dest must be wave-uniform-base + lane*16)
__device__ __forceinline__ void gload_lds16(const void* g, void* l) {
  __builtin_amdgcn_global_load_lds(
      (const __attribute__((address_space(1))) unsigned int*)g,
      (__attribute__((address_space(3))) unsigned int*)l, 16, 0, 0);
}

// ---------------------------------------------------------------------------
// Generic MFMA GEMM core.  C[M,N] = A[M,K] @ B[K,N], B given as BT[N][K].
// SPLIT: fp16 hi/lo planes, compute hh + hl + lh.
// EPI: 0 f32; 1 f32+residual; 2 split fp16; 3 relu^2 fp16; 4 fp16.
// USECNT/GATHER: MoE ragged M + row gather.
// ASYNC: 0 reg-stage; 1 gload A+B prefetch dbuf; 2 A reg-prefetch + B gload.
// KS: K-split (pays only when it truly doubles blocks/CU — r13 lesson).
// r15 lesson: tile-shrink (SMALLM) raises occupancy but doubles staging work;
// the m97 structure is staging-throughput-bound -> both knobs fail for qkv.
// Fragment maps (16x16x32 f16): A/B elem j of lane l = T[l&15][8*(l>>4)+j];
// C/D: col=l&15, row=(l>>4)*4+j.
// ---------------------------------------------------------------------------
struct GemmP {
  const h16* Ah; const h16* Al;
  const h16* Bh; const h16* Bl;
  float* Cf; h16* Ch; h16* Cl;
  const float* R;
  const int* cnt; const int* off; const int* perm;
  long sAz, sBz, sCzHi, sCzLo;
  int M, N, K, lda, ldb, ldc;
  int zAoff, zBoff, zCoff, bzShift, czHiShift, czLoMask;
  float outScale;
};

template <int SPLIT, int EPI, int USECNT, int GATHER, int ASYNC, int KS>
__global__ __launch_bounds__(256, 4) void gemm_k(GemmP p) {
  constexpr int NP = SPLIT ? 2 : 1;
  constexpr int NBUF = (ASYNC >= 1) ? 2 : 1;
  constexpr int APAD = (ASYNC == 1) ? 32 : 40;  // gload rows must be linear
  constexpr int BPAD = (ASYNC >= 1) ? 32 : 40;
  __shared__ __align__(16) h16 As[NBUF][NP][128][APAD];
  __shared__ __align__(16) h16 Bs[NBUF][NP][128][BPAD];
  __shared__ int permLds[GATHER ? 128 : 1];

  // bijective 8-XCD swizzle of the flattened (bm,bn) index
  const int nwg = gridDim.x * gridDim.y;
  const int flat = blockIdx.y * gridDim.x + blockIdx.x;
  const int q8 = nwg >> 3, r8 = nwg & 7;
  const int xcd = flat & 7, sub = flat >> 3;
  const int swz = (xcd < r8 ? xcd * (q8 + 1) : r8 * (q8 + 1) + (xcd - r8) * q8) + sub;
  const int bm = swz % gridDim.x, bn = swz / gridDim.x;
  const int zl = blockIdx.z;

  int Meff, rowbase;
  if (USECNT) {
    Meff = p.cnt[zl]; rowbase = p.off[zl];
    if (bm * 128 >= Meff) return;
  } else { Meff = p.M; rowbase = 0; }

  const int zA = zl + p.zAoff, zB = zl + p.zBoff, zC = zl + p.zCoff;
  const h16* Ah = p.Ah + (size_t)zA * p.sAz;
  const h16* Al = SPLIT ? p.Al + (size_t)zA * p.sAz : (const h16*)0;
  const size_t bofs = (size_t)(zB >> p.bzShift) * p.sBz;
  const h16* Bh = p.Bh + bofs;
  const h16* Bl = SPLIT ? p.Bl + bofs : (const h16*)0;
  const size_t cofs = (size_t)(zC >> p.czHiShift) * p.sCzHi +
                      (size_t)(zC & p.czLoMask) * p.sCzLo;

  const int tid = threadIdx.x;
  const int lane = tid & 63;
  const int wid = tid >> 6, wr = wid >> 1, wc = wid & 1;
  const int fr = lane & 15, fq = lane >> 4;

  if (GATHER) {
    if (tid < 128) {
      const int local = bm * 128 + tid;
      permLds[tid] = (local < Meff) ? p.perm[rowbase + local] : -1;
    }
    __syncthreads();
  }

  const long arow0 = (long)rowbase + (long)bm * 128;  // contiguous-A base

  const f32x4 fz = {0.f, 0.f, 0.f, 0.f};
  f32x4 acc[4][4];
#pragma unroll
  for (int m = 0; m < 4; ++m)
#pragma unroll
    for (int n = 0; n < 4; ++n) acc[m][n] = fz;

  const int nkt = p.K / 32;
  const int ktBeg = (KS > 1) ? zl * (nkt / KS) : 0;
  const int ktEnd = (KS > 1) ? ktBeg + nkt / KS : nkt;

  auto compute = [&](int buf) {
    half8 af[NP][4], bf[NP][4];
#pragma unroll
    for (int m = 0; m < 4; ++m) {
      const int r = wr * 64 + m * 16 + fr;
      af[0][m] = *(const half8*)&As[buf][0][r][fq * 8];
      if (SPLIT) af[1][m] = *(const half8*)&As[buf][1][r][fq * 8];
    }
#pragma unroll
    for (int n = 0; n < 4; ++n) {
      const int c = wc * 64 + n * 16 + fr;
      bf[0][n] = *(const half8*)&Bs[buf][0][c][fq * 8];
      if (SPLIT) bf[1][n] = *(const half8*)&Bs[buf][1][c][fq * 8];
    }
#pragma unroll
    for (int m = 0; m < 4; ++m)
#pragma unroll
      for (int n = 0; n < 4; ++n) {
        acc[m][n] = __builtin_amdgcn_mfma_f32_16x16x32_f16(af[0][m], bf[0][n], acc[m][n], 0, 0, 0);
        if (SPLIT) {
          acc[m][n] = __builtin_amdgcn_mfma_f32_16x16x32_f16(af[0][m], bf[1][n], acc[m][n], 0, 0, 0);
          acc[m][n] = __builtin_amdgcn_mfma_f32_16x16x32_f16(af[1][m], bf[0][n], acc[m][n], 0, 0, 0);
        }
      }
  };

  if constexpr (ASYNC == 1) {
    auto stage = [&](int buf, int kt) {
      const int kb = kt * 32;
#pragma unroll
      for (int it = 0; it < 2; ++it) {
        const int d = (tid + it * 256) * 16;  // byte offset within 8KB plane
        const int row = d >> 6;               // 0..127
        const int oct = (d >> 4) & 3;         // k-octet 0..3
        const size_t gb = ((size_t)(bn * 128 + row)) * p.ldb + kb + oct * 8;
        gload_lds16(Bh + gb, (char*)&Bs[buf][0][0][0] + d);
        if (SPLIT) gload_lds16(Bl + gb, (char*)&Bs[buf][1][0][0] + d);
        const size_t ga = (size_t)(arow0 + row) * p.lda + kb + oct * 8;
        gload_lds16(Ah + ga, (char*)&As[buf][0][0][0] + d);
        if (SPLIT) gload_lds16(Al + ga, (char*)&As[buf][1][0][0] + d);
      }
    };
    stage(0, ktBeg);
    __syncthreads();
    int cur = 0;
    for (int kt = ktBeg; kt < ktEnd; ++kt) {
      if (kt + 1 < ktEnd) stage(cur ^ 1, kt + 1);  // prefetch flies during MFMA
      compute(cur);
      __syncthreads();
      cur ^= 1;
    }
  } else if constexpr (ASYNC == 2) {
    // A reg-prefetch (gather) + B gload dbuf; single barrier per K-tile.
    half8 aPre[2];
    auto loadA = [&](int kt) {
#pragma unroll
      for (int s = 0; s < 2; ++s) {
        const int seg = tid * 2 + s;
        const int row = seg >> 2, ks = (seg & 3) * 8;
        bool av; long arow;
        if (GATHER) { const int tk2 = permLds[row]; av = (tk2 >= 0); arow = tk2; }
        else { const int local = bm * 128 + row; av = (local < Meff); arow = (long)rowbase + local; }
        half8 v = {0,0,0,0,0,0,0,0};
        if (av) v = *(const half8*)(Ah + arow * (size_t)p.lda + kt * 32 + ks);
        aPre[s] = v;
      }
    };
    auto stageB2 = [&](int buf, int kt) {
      const int kb = kt * 32;
#pragma unroll
      for (int it = 0; it < 2; ++it) {
        const int d = (tid + it * 256) * 16;
        const int row = d >> 6;
        const int oct = (d >> 4) & 3;
        const size_t gb = ((size_t)(bn * 128 + row)) * p.ldb + kb + oct * 8;
        gload_lds16(Bh + gb, (char*)&Bs[buf][0][0][0] + d);
      }
    };
    loadA(ktBeg);
    stageB2(0, ktBeg);
    int cur = 0;
    for (int kt = ktBeg; kt < ktEnd; ++kt) {
#pragma unroll
      for (int s = 0; s < 2; ++s) {  // write prefetched A regs -> LDS
        const int seg = tid * 2 + s;
        const int row = seg >> 2, ks = (seg & 3) * 8;
        *(half8*)&As[cur][0][row][ks] = aPre[s];
      }
      __syncthreads();  // drains B gload(cur); syncs A writes
      if (kt + 1 < ktEnd) { loadA(kt + 1); stageB2(cur ^ 1, kt + 1); }
      compute(cur);
      cur ^= 1;
    }
  } else {
    for (int kt = ktBeg; kt < ktEnd; ++kt) {
      if (kt != ktBeg) __syncthreads();
      const int kb = kt * 32;
#pragma unroll
      for (int s = 0; s < 2; ++s) {
        const int seg = tid * 2 + s;  // 128 rows x 4 octets
        const int row = seg >> 2, ks = (seg & 3) * 8;
        const int local = bm * 128 + row;
        bool av; long arow;
        if (GATHER) { const int tk2 = permLds[row]; av = (tk2 >= 0); arow = tk2; }
        else { av = (local < Meff); arow = (long)rowbase + local; }
        half8 vh = {0,0,0,0,0,0,0,0}, vl = {0,0,0,0,0,0,0,0};
        if (av) {
          vh = *(const half8*)(Ah + arow * (size_t)p.lda + kb + ks);
          if (SPLIT) vl = *(const half8*)(Al + arow * (size_t)p.lda + kb + ks);
        }
        *(half8*)&As[0][0][row][ks] = vh;
        if (SPLIT) *(half8*)&As[0][1][row][ks] = vl;
        const long brow = (long)bn * 128 + row;
        *(half8*)&Bs[0][0][row][ks] = *(const half8*)(Bh + brow * (size_t)p.ldb + kb + ks);
        if (SPLIT)
          *(half8*)&Bs[0][1][row][ks] = *(const half8*)(Bl + brow * (size_t)p.ldb + kb + ks);
      }
      __syncthreads();
      compute(0);
    }
  }

#pragma unroll
  for (int m = 0; m < 4; ++m)
#pragma unroll
    for (int n = 0; n < 4; ++n)
#pragma unroll
      for (int j = 0; j < 4; ++j) {
        const int rl = wr * 64 + m * 16 + fq * 4 + j;
        const int cl = wc * 64 + n * 16 + fr;
        const int local = bm * 128 + rl;
        if (local >= Meff) continue;
        const size_t idx = cofs + ((size_t)rowbase + local) * p.ldc + (size_t)bn * 128 + cl;
        const float v = acc[m][n][j] * p.outScale;
        if (EPI == 0) p.Cf[idx] = v;
        else if (EPI == 1) p.Cf[idx] = v + p.R[idx];
        else if (EPI == 2) {
          const h16 hh = (h16)v;
          p.Ch[idx] = hh; p.Cl[idx] = (h16)(v - (float)hh);
        } else if (EPI == 3) {
          const float r2 = v > 0.f ? v * v : 0.f;
          p.Ch[idx] = (h16)r2;
        } else {
          p.Ch[idx] = (h16)v;
        }
      }
}

// ---------------------------------------------------------------------------
// Flash attention, causal KV-split + T14 async-STAGE prefetch (round-9 form).
// ---------------------------------------------------------------------------
__global__ __launch_bounds__(512, 4) void flash_k(
    const h16* __restrict__ Qh, const h16* __restrict__ Ql,
    const h16* __restrict__ Kh, const h16* __restrict__ Kl,
    const h16* __restrict__ Vh, const h16* __restrict__ Vl,
    h16* __restrict__ yh, h16* __restrict__ yl,
    float* __restrict__ yp, float* __restrict__ mp, float* __restrict__ lp) {
  __shared__ __align__(16) h16 Ks[2][32][136];   // [plane][kv][d]  (B of QK^T)
  __shared__ __align__(16) h16 Vs[2][128][40];   // [plane][d][kv]  (B of PV)
  __shared__ __align__(16) h16 Ps[8][2][16][40]; // wave-private P transpose slab

  // heavy-first item table: {qb, chunk, isFull}
  const int QBT[12]  = {3, 7, 7, 6, 6, 2, 5, 5, 4, 4, 1, 0};
  const int CHT[12]  = {0, 0, 1, 0, 1, 0, 0, 1, 0, 1, 0, 0};
  const int FULT[12] = {1, 0, 0, 0, 0, 1, 0, 0, 0, 0, 1, 1};

  const int z = blockIdx.x, item = blockIdx.y;
  const int qb = QBT[item], chunk = CHT[item], full = FULT[item];
  const int nt = (qb + 1) * 4;
  const int tBeg = full ? 0 : (chunk ? nt / 2 : 0);
  const int tEnd = full ? nt : (chunk ? nt : nt / 2);

  const int b = z >> 4, h = z & 15;
  const size_t qoff = (size_t)z * 131072;
  const size_t koff = (size_t)(b * 4 + (h >> 2)) * 131072;

  const int tid = threadIdx.x;
  const int lane = tid & 63, w = tid >> 6;
  const int fr = lane & 15, fq = lane >> 4;

  // ---- Q fragments (persistent) ----
  const int qrow = qb * 128 + w * 16 + fr;
  half8 qa[2][4];
#pragma unroll
  for (int kt = 0; kt < 4; ++kt) {
    qa[0][kt] = *(const half8*)(Qh + qoff + (size_t)qrow * 128 + kt * 32 + fq * 8);
    qa[1][kt] = *(const half8*)(Ql + qoff + (size_t)qrow * 128 + kt * 32 + fq * 8);
  }

  const int kRow = tid >> 4, kSeg = tid & 15;   // K: 32 rows x 16 segs
  const int vRow = tid >> 2, vSeg = tid & 3;    // V: 128 rows x 4 segs

  half8 kreg[2], vreg[2];
  auto loadKV = [&](int t) {
    const int kvb = t * 32;
#pragma unroll
    for (int pl = 0; pl < 2; ++pl) {
      const h16* kp = pl ? Kl : Kh;
      const h16* vp = pl ? Vl : Vh;
      kreg[pl] = *(const half8*)(kp + koff + (size_t)(kvb + kRow) * 128 + kSeg * 8);
      vreg[pl] = *(const half8*)(vp + koff + (size_t)vRow * 1024 + kvb + vSeg * 8);
    }
  };

  const f32x4 fz = {0.f, 0.f, 0.f, 0.f};
  f32x4 y[8];
#pragma unroll
  for (int n = 0; n < 8; ++n) y[n] = fz;
  float mrow[4] = {-3.0e38f, -3.0e38f, -3.0e38f, -3.0e38f};
  float lrow[4] = {0.f, 0.f, 0.f, 0.f};

  loadKV(tBeg);
  for (int t = tBeg; t < tEnd; ++t) {
    const int kvb = t * 32;
    if (t != tBeg) __syncthreads();  // all waves done reading previous tile
#pragma unroll
    for (int pl = 0; pl < 2; ++pl) {
      *(half8*)&Ks[pl][kRow][kSeg * 8] = kreg[pl];
      *(half8*)&Vs[pl][vRow][vSeg * 8] = vreg[pl];
    }
    __syncthreads();
    if (t + 1 < tEnd) loadKV(t + 1);  // next tile's loads fly under compute

    // ---- S = Q @ K^T ----
    f32x4 sf[2] = {fz, fz};
#pragma unroll
    for (int n = 0; n < 2; ++n)
#pragma unroll
      for (int kt = 0; kt < 4; ++kt) {
        const half8 bh2 = *(const half8*)&Ks[0][n * 16 + fr][kt * 32 + fq * 8];
        const half8 bl2 = *(const half8*)&Ks[1][n * 16 + fr][kt * 32 + fq * 8];
        sf[n] = __builtin_amdgcn_mfma_f32_16x16x32_f16(qa[0][kt], bh2, sf[n], 0, 0, 0);
        sf[n] = __builtin_amdgcn_mfma_f32_16x16x32_f16(qa[0][kt], bl2, sf[n], 0, 0, 0);
        sf[n] = __builtin_amdgcn_mfma_f32_16x16x32_f16(qa[1][kt], bh2, sf[n], 0, 0, 0);
      }

    if (kvb + 31 > qb * 128) {
#pragma unroll
      for (int n = 0; n < 2; ++n)
#pragma unroll
        for (int j = 0; j < 4; ++j) {
          const int kvg = kvb + n * 16 + fr;
          const int qg = qb * 128 + w * 16 + fq * 4 + j;
          if (kvg > qg) sf[n][j] = -3.0e38f;
        }
    }

    float al[4];
#pragma unroll
    for (int j = 0; j < 4; ++j) {
      float tm = fmaxf(sf[0][j], sf[1][j]);
#pragma unroll
      for (int msk = 1; msk < 16; msk <<= 1) tm = fmaxf(tm, __shfl_xor(tm, msk, 16));
      const float mn = fmaxf(mrow[j], tm);
      al[j] = __expf(mrow[j] - mn);
      mrow[j] = mn;
      sf[0][j] = __expf(sf[0][j] - mn);
      sf[1][j] = __expf(sf[1][j] - mn);
      float ts = sf[0][j] + sf[1][j];
#pragma unroll
      for (int msk = 1; msk < 16; msk <<= 1) ts += __shfl_xor(ts, msk, 16);
      lrow[j] = lrow[j] * al[j] + ts;
    }
#pragma unroll
    for (int n = 0; n < 8; ++n)
#pragma unroll
      for (int j = 0; j < 4; ++j) y[n][j] *= al[j];

#pragma unroll
    for (int n = 0; n < 2; ++n)
#pragma unroll
      for (int j = 0; j < 4; ++j) {
        const float pp = sf[n][j] * 1024.f;
        const h16 hh = (h16)pp;
        Ps[w][0][fq * 4 + j][n * 16 + fr] = hh;
        Ps[w][1][fq * 4 + j][n * 16 + fr] = (h16)(pp - (float)hh);
      }

    const half8 pah = *(const half8*)&Ps[w][0][fr][fq * 8];
    const half8 pal = *(const half8*)&Ps[w][1][fr][fq * 8];
#pragma unroll
    for (int n = 0; n < 8; ++n) {
      const half8 vh2 = *(const half8*)&Vs[0][n * 16 + fr][fq * 8];
      const half8 vl2 = *(const half8*)&Vs[1][n * 16 + fr][fq * 8];
      y[n] = __builtin_amdgcn_mfma_f32_16x16x32_f16(pah, vh2, y[n], 0, 0, 0);
      y[n] = __builtin_amdgcn_mfma_f32_16x16x32_f16(pah, vl2, y[n], 0, 0, 0);
      y[n] = __builtin_amdgcn_mfma_f32_16x16x32_f16(pal, vh2, y[n], 0, 0, 0);
    }
  }

  if (full) {
#pragma unroll
    for (int n = 0; n < 8; ++n)
#pragma unroll
      for (int j = 0; j < 4; ++j) {
        const int row = qb * 128 + w * 16 + fq * 4 + j;
        const int col = h * 128 + n * 16 + fr;
        const float v = y[n][j] / (1024.f * lrow[j]);
        const size_t idx = ((size_t)(b * 1024 + row)) * 2048 + col;
        const h16 hh = (h16)v;
        yh[idx] = hh; yl[idx] = (h16)(v - (float)hh);
      }
  } else {
#pragma unroll
    for (int j = 0; j < 4; ++j) {
      const int qrl = w * 16 + fq * 4 + j;              // 0..127 local row
      const int q512 = (qb - 4) * 128 + qrl;            // 0..511
      const size_t rbase = (((size_t)chunk * 32 + z) * 512 + q512);
#pragma unroll
      for (int n = 0; n < 8; ++n)
        yp[rbase * 128 + n * 16 + fr] = y[n][j];
      if (fr == 0) { mp[rbase] = mrow[j]; lp[rbase] = lrow[j]; }
    }
  }
}

// ---------------------------------------------------------------------------
// Merge the two KV-chunk partials for qb in [4,8).  float4-vectorized.
// ---------------------------------------------------------------------------
__global__ void comb_k(const float* __restrict__ yp, const float* __restrict__ mp,
                       const float* __restrict__ lp,
                       h16* __restrict__ yh, h16* __restrict__ yl) {
  const int qh = blockIdx.x, z = blockIdx.y;
  const int b = z >> 4, h = z & 15;
  const int tid = threadIdx.x;
  for (int i4 = tid; i4 < 4096; i4 += 256) {   // 128 rows x 32 float4
    const int r = i4 >> 5, d4 = (i4 & 31) * 4;
    const int q512 = qh * 128 + r;
    const size_t r0 = ((size_t)0 * 32 + z) * 512 + q512;
    const size_t r1 = ((size_t)1 * 32 + z) * 512 + q512;
    const float m1 = mp[r0], m2 = mp[r1];
    const float l1 = lp[r0], l2 = lp[r1];
    const float M = fmaxf(m1, m2);
    const float e1 = __expf(m1 - M), e2 = __expf(m2 - M);
    const float inv = 1.f / (1024.f * (l1 * e1 + l2 * e2));
    const f32x4 a = *(const f32x4*)(yp + r0 * 128 + d4);
    const f32x4 c = *(const f32x4*)(yp + r1 * 128 + d4);
    const size_t o = ((size_t)(b * 1024 + (4 + qh) * 128 + r)) * 2048 + h * 128 + d4;
#pragma unroll
    for (int j = 0; j < 4; ++j) {
      const float v = (a[j] * e1 + c[j] * e2) * inv;
      const h16 hh = (h16)v;
      yh[o + j] = hh; yl[o + j] = (h16)(v - (float)hh);
    }
  }
}

// ---------------------------------------------------------------------------
// Weight transpose + fp16 hi/lo split, vectorized half8 stores.
// ---------------------------------------------------------------------------
__global__ void tsplit_k(const float* __restrict__ W, h16* __restrict__ Th,
                         h16* __restrict__ Tl, int K, int N, float scale, int wantLo) {
  const size_t eoff = (size_t)blockIdx.z * (size_t)K * N;
  W += eoff; Th += eoff; if (Tl) Tl += eoff;
  __shared__ float tile[32][33];
  const int nt = blockIdx.x * 32, kt = blockIdx.y * 32;
  const int c = threadIdx.x & 31, r0 = threadIdx.x >> 5;
#pragma unroll
  for (int rr = 0; rr < 4; ++rr)
    tile[r0 + rr * 8][c] = W[(size_t)(kt + r0 + rr * 8) * N + nt + c];
  __syncthreads();
  const int t = threadIdx.x;
  const int pl = t >> 7;                       // 0 = hi, 1 = lo
  if (pl == 1 && !wantLo) return;
  const int n = (t & 127) >> 2, ks = (t & 3) * 8;
  half8 o;
#pragma unroll
  for (int i = 0; i < 8; ++i) {
    const float v = tile[ks + i][n] * scale;
    const h16 hh = (h16)v;
    o[i] = pl ? (h16)(v - (float)hh) : hh;
  }
  h16* dst = pl ? Tl : Th;
  *(half8*)&dst[(size_t)(nt + n) * K + kt + ks] = o;
}

// ---------------------------------------------------------------------------
// Row RMS-norm (C=2048) -> fp16 hi (+optional lo).  float4/half8 vectorized.
// ---------------------------------------------------------------------------
template <int WLO>
__global__ void rms_k(const float* __restrict__ X, h16* __restrict__ H,
                      h16* __restrict__ L) {
  const int row = blockIdx.x;
  const float* x = X + (size_t)row * 2048;
  __shared__ float red[256];
  const int tid = threadIdx.x;
  const int c0 = tid * 8;
  float vreg[8];
  float ss = 0.f;
#pragma unroll
  for (int h = 0; h < 2; ++h) {
    const f32x4 a = *(const f32x4*)(x + c0 + h * 4);
#pragma unroll
    for (int j = 0; j < 4; ++j) { vreg[h * 4 + j] = a[j]; ss += a[j] * a[j]; }
  }
  red[tid] = ss; __syncthreads();
  for (int t = 128; t > 0; t >>= 1) {
    if (tid < t) red[tid] += red[tid + t];
    __syncthreads();
  }
  const float sc = rsqrtf(red[0] * (1.f / 2048.f) + EPS_RMS);
  const size_t ob = (size_t)row * 2048 + c0;
  half8 oh, ol;
#pragma unroll
  for (int i = 0; i < 8; ++i) {
    const float v = vreg[i] * sc;
    const h16 hh = (h16)v;
    oh[i] = hh;
    if (WLO) ol[i] = (h16)(v - (float)hh);
  }
  *(half8*)&H[ob] = oh;
  if (WLO) *(half8*)&L[ob] = ol;
}

// ---------------------------------------------------------------------------
// Fused: x2 = x + P0 + P1 (Wo split-K partials), rms(x2) -> xfh, router.
// float4 contiguous loads (16B/lane); row segment of 8 cols per thread.
// ---------------------------------------------------------------------------
__global__ void rmsrouter_k(const float* __restrict__ x, const float* __restrict__ P0,
                            const float* __restrict__ P1, const float* __restrict__ Wr,
                            float* __restrict__ x2, h16* __restrict__ xfh,
                            int* __restrict__ idx2, float* __restrict__ g2,
                            int* __restrict__ cnt) {
  const int n = blockIdx.x, tid = threadIdx.x;
  __shared__ float redss[256];
  __shared__ float red8[256][8];
  const size_t rb = (size_t)n * 2048;
  const int c0 = tid * 8;
  float vreg[8];
  float ss = 0.f;
  float part[8] = {0, 0, 0, 0, 0, 0, 0, 0};
#pragma unroll
  for (int h = 0; h < 2; ++h) {
    const size_t o = rb + c0 + h * 4;
    const f32x4 a = *(const f32x4*)(x + o);
    const f32x4 b = *(const f32x4*)(P0 + o);
    const f32x4 c = *(const f32x4*)(P1 + o);
    f32x4 v;
#pragma unroll
    for (int j = 0; j < 4; ++j) {
      v[j] = a[j] + b[j] + c[j];
      vreg[h * 4 + j] = v[j];
      ss += v[j] * v[j];
      const float* w2 = Wr + (size_t)(c0 + h * 4 + j) * 8;
#pragma unroll
      for (int e = 0; e < 8; ++e) part[e] += v[j] * w2[e];
    }
    *(f32x4*)(x2 + o) = v;
  }
  redss[tid] = ss;
#pragma unroll
  for (int e = 0; e < 8; ++e) red8[tid][e] = part[e];
  __syncthreads();
  for (int t = 128; t > 0; t >>= 1) {
    if (tid < t) {
      redss[tid] += redss[tid + t];
#pragma unroll
      for (int e = 0; e < 8; ++e) red8[tid][e] += red8[tid + t][e];
    }
    __syncthreads();
  }
  const float sc = rsqrtf(redss[0] * (1.f / 2048.f) + EPS_RMS);
  half8 xo;
#pragma unroll
  for (int i = 0; i < 8; ++i) xo[i] = (h16)(vreg[i] * sc);
  *(half8*)&xfh[rb + c0] = xo;
  if (tid == 0) {
    float l[8];
#pragma unroll
    for (int e = 0; e < 8; ++e) l[e] = red8[0][e] * sc;
    int i1 = 0;
    for (int e = 1; e < 8; ++e) if (l[e] > l[i1]) i1 = e;
    int i2 = (i1 == 0) ? 1 : 0;
    for (int e = 0; e < 8; ++e) if (e != i1 && l[e] > l[i2]) i2 = e;
    const float e2 = __expf(l[i2] - l[i1]);
    const float inv = 1.f / (1.f + e2);
    idx2[n * 2] = i1; idx2[n * 2 + 1] = i2;
    g2[n * 2] = inv; g2[n * 2 + 1] = e2 * inv;
    atomicAdd(&cnt[i1], 1); atomicAdd(&cnt[i2], 1);
  }
}

// ---------------------------------------------------------------------------
// RoPE + per-head RMS on q/k, split fp16; V stored transposed [z][d][t].
// ---------------------------------------------------------------------------
__global__ void rope_k(const float* __restrict__ qkv, const float* __restrict__ cosT,
                       const float* __restrict__ sinT,
                       h16* __restrict__ Qh, h16* __restrict__ Ql,
                       h16* __restrict__ Kh, h16* __restrict__ Kl,
                       h16* __restrict__ Vh, h16* __restrict__ Vl) {
  const int tok = blockIdx.x;
  const int b = tok >> 10, t = tok & 1023;
  const int u = blockIdx.y, d = threadIdx.x;
  __shared__ float buf[128];
  __shared__ float red[128];
  int col;
  if (u < 16) col = u * 128 + d;
  else if (u < 20) col = 2048 + (u - 16) * 128 + d;
  else col = 2560 + (u - 20) * 128 + d;
  float v = qkv[(size_t)tok * 3072 + col];
  if (u < 20) {
    buf[d] = v; __syncthreads();
    float r;
    if (d < 64) {
      const float c = cosT[t * 64 + d], s = sinT[t * 64 + d];
      r = buf[d] * c + buf[d + 64] * s;
    } else {
      const float c = cosT[t * 64 + d - 64], s = sinT[t * 64 + d - 64];
      r = -buf[d - 64] * s + buf[d] * c;
    }
    red[d] = r * r; __syncthreads();
    for (int tt = 64; tt > 0; tt >>= 1) {
      if (d < tt) red[d] += red[d + tt];
      __syncthreads();
    }
    v = r * rsqrtf(red[0] * (1.f / 128.f) + EPS_RMS);
    if (u < 16) v *= 0.08838834764831845f;  // 1/sqrt(128)
  }
  const h16 hh = (h16)v;
  const h16 lo = (h16)(v - (float)hh);
  if (u < 16) {
    const size_t o2 = (((size_t)(b * 16 + u)) * 1024 + t) * 128 + d;
    Qh[o2] = hh; Ql[o2] = lo;
  } else if (u < 20) {
    const size_t o2 = (((size_t)(b * 4 + (u - 16))) * 1024 + t) * 128 + d;
    Kh[o2] = hh; Kl[o2] = lo;
  } else {
    const size_t o2 = ((size_t)(b * 4 + (u - 20))) * 131072 + (size_t)d * 1024 + t;
    Vh[o2] = hh; Vl[o2] = lo;
  }
}

__global__ void zero8_k(int* __restrict__ p) {
  if (threadIdx.x < 16 && blockIdx.x == 0) p[threadIdx.x] = 0;
}

// scan + virtual dense expert 8 (cnt=2048, off=4096) for the fused MoE GEMMs
__global__ void scan_k(int* __restrict__ cnt, int* __restrict__ off,
                       int* __restrict__ base) {
  if (threadIdx.x == 0 && blockIdx.x == 0) {
    int a = 0;
    for (int e = 0; e < 8; ++e) { off[e] = a; base[e] = a; a += cnt[e]; }
    off[8] = a; base[8] = a; cnt[8] = 2048;  // a == 4096 (2 experts/token)
  }
}

// assign + identity perm for the virtual dense expert
__global__ void assign_k(const int* __restrict__ idx2, int* __restrict__ base,
                         int* __restrict__ perm, int* __restrict__ pos2) {
  const int n = blockIdx.x * 256 + threadIdx.x;
  if (n >= 2048) return;
  perm[4096 + n] = n;
  for (int j = 0; j < 2; ++j) {
    const int e = idx2[n * 2 + j];
    const int pos = atomicAdd(&base[e], 1);
    perm[pos] = n;
    pos2[n * 2 + j] = pos;
  }
}

// out = x2 + shared(rpx rows 4096+) + gated routed; half8/float4 vectorized.
__global__ void combine_k(const float* __restrict__ x2, const h16* __restrict__ rpx,
                          const int* __restrict__ pos2,
                          const float* __restrict__ g2, float* __restrict__ out) {
  const int n = blockIdx.x;
  const int p0 = pos2[n * 2], p1 = pos2[n * 2 + 1];
  const float g0 = g2[n * 2], g1 = g2[n * 2 + 1];
  const int c0 = threadIdx.x * 8;
  const size_t i0 = (size_t)n * 2048 + c0;
  const half8 shv = *(const half8*)(rpx + (size_t)(4096 + n) * 2048 + c0);
  const half8 r0v = *(const half8*)(rpx + (size_t)p0 * 2048 + c0);
  const half8 r1v = *(const half8*)(rpx + (size_t)p1 * 2048 + c0);
#pragma unroll
  for (int h = 0; h < 2; ++h) {
    const f32x4 xa = *(const f32x4*)(x2 + i0 + h * 4);
    f32x4 o;
#pragma unroll
    for (int j = 0; j < 4; ++j) {
      const int k = h * 4 + j;
      o[j] = xa[j] + (float)shv[k] + g0 * (float)r0v[k] + g1 * (float)r1v[k];
    }
    *(f32x4*)(out + i0 + h * 4) = o;
  }
}

// ---------------------------------------------------------------------------
extern "C" void kernel_launch(void* const* d_in, const int* in_sizes, int n_in,
                              void* d_out, int out_size, void* d_ws, size_t ws_size,
                              hipStream_t stream) {
  const float* x    = (const float*)d_in[0];
  const float* cosT = (const float*)d_in[1];
  const float* sinT = (const float*)d_in[2];
  const float* Wq   = (const float*)d_in[3];
  const float* Wk   = (const float*)d_in[4];
  const float* Wv   = (const float*)d_in[5];
  const float* Wo   = (const float*)d_in[6];
  const float* Wr   = (const float*)d_in[7];
  const float* Ws1  = (const float*)d_in[8];
  const float* Ws2  = (const float*)d_in[9];
  const float* We1  = (const float*)d_in[10];
  const float* We2  = (const float*)d_in[11];
  float* out = (float*)d_out;

  // -------- fixed 123 MiB workspace layout (lifetime-overlapped regions) ----
  unsigned char* W = (unsigned char*)d_ws;
  int*   idx2 = (int*)(W + 0);              // 16KB
  float* g2   = (float*)(W + 16 * 1024);    // 16KB
  int*   cnt  = (int*)(W + 32 * 1024);
  int*   offs = (int*)(W + 33 * 1024);
  int*   base = (int*)(W + 34 * 1024);
  int*   pos2 = (int*)(W + 36 * 1024);      // 16KB
  int*   perm = (int*)(W + 56 * 1024);      // 24KB (6144 ints)
  // R1 [1,25): W1 (Wqkv split) -> W2 (Wo split)
  h16* W1h = (h16*)(W + 1 * MiB);
  h16* W1l = (h16*)(W + 13 * MiB);
  h16* W2h = (h16*)(W + 1 * MiB);
  h16* W2l = (h16*)(W + 9 * MiB);
  // R2 [25,41): xn -> y -> xf
  h16* xnh = (h16*)(W + 25 * MiB);
  h16* xnl = (h16*)(W + 33 * MiB);
  h16* yh  = (h16*)(W + 25 * MiB);
  h16* yl  = (h16*)(W + 33 * MiB);
  h16* xfh = (h16*)(W + 25 * MiB);
  // R3 [41,65): qkv f32 (24 MiB) -> flash partials -> Wo partials -> hcomb
  float* qkv = (float*)(W + 41 * MiB);
  float* ypart = (float*)(W + 41 * MiB);   // 16 MiB: [2][32][512][128] f32
  float* mpart = (float*)(W + 57 * MiB);
  float* lpart = (float*)(W + 58 * MiB);
  float* wopart = (float*)(W + 41 * MiB);  // 2 x 16 MiB f32 planes (41,57)
  h16* hcomb = (h16*)(W + 41 * MiB);       // 6144x512 h16 (6 MiB)
  // R4 [65,89): Q/K/V split -> rpx (6144x2048 h16, 24MiB)
  h16* Qh = (h16*)(W + 65 * MiB);
  h16* Ql = (h16*)(W + 73 * MiB);
  h16* Kh = (h16*)(W + 81 * MiB);
  h16* Kl = (h16*)(W + 83 * MiB);
  h16* Vh = (h16*)(W + 85 * MiB);
  h16* Vl = (h16*)(W + 87 * MiB);
  h16* rpx = (h16*)(W + 65 * MiB);
  // R5 [89,105): x2 f32
  float* x2 = (float*)(W + 89 * MiB);
  // R6 [105,123): MoE weights, 9 planes x 2MiB (plane 8 = shared expert)
  h16* WeT = (h16*)(W + 105 * MiB);
  h16* WsPlane8 = WeT + (size_t)8 * 1048576;

  const float WS = 64.f;
  const float IWS = 1.f / 64.f;

  // ---- phase 1: Wqkv prep, rms(x), qkv GEMM ----
  tsplit_k<<<dim3(64, 64, 1), 256, 0, stream>>>(Wq, W1h, W1l, 2048, 2048, WS, 1);
  tsplit_k<<<dim3(16, 64, 1), 256, 0, stream>>>(Wk, W1h + (size_t)2048 * 2048,
                                                W1l + (size_t)2048 * 2048, 2048, 512, WS, 1);
  tsplit_k<<<dim3(16, 64, 1), 256, 0, stream>>>(Wv, W1h + (size_t)2560 * 2048,
                                                W1l + (size_t)2560 * 2048, 2048, 512, WS, 1);
  zero8_k<<<1, 64, 0, stream>>>(cnt);
  rms_k<1><<<2048, 256, 0, stream>>>(x, xnh, xnl);
  {
    GemmP p{};
    p.Ah = xnh; p.Al = xnl; p.Bh = W1h; p.Bl = W1l; p.Cf = qkv;
    p.M = 2048; p.N = 3072; p.K = 2048; p.lda = 2048; p.ldb = 2048; p.ldc = 3072;
    p.outScale = IWS;
    gemm_k<1, 0, 0, 0, 1, 1><<<dim3(16, 24, 1), 256, 0, stream>>>(p);
  }

  // ---- phase 2: rope + head-rms (qkv dead after) ----
  rope_k<<<dim3(2048, 24, 1), 128, 0, stream>>>(qkv, cosT, sinT, Qh, Ql, Kh, Kl, Vh, Vl);

  // ---- phase 3: Wo prep + flash attention (KV-split, heavy-first) + merge --
  tsplit_k<<<dim3(64, 64, 1), 256, 0, stream>>>(Wo, W2h, W2l, 2048, 2048, WS, 1);
  flash_k<<<dim3(32, 12, 1), 512, 0, stream>>>(Qh, Ql, Kh, Kl, Vh, Vl, yh, yl,
                                               ypart, mpart, lpart);
  comb_k<<<dim3(4, 32, 1), 256, 0, stream>>>(ypart, mpart, lpart, yh, yl);

  // ---- phase 4: Wo split-K x2 -> f32 partials (sum fused into rmsrouter) ---
  {
    GemmP p{};
    p.Ah = yh; p.Al = yl; p.Bh = W2h; p.Bl = W2l; p.Cf = wopart;
    p.M = 2048; p.N = 2048; p.K = 2048; p.lda = 2048; p.ldb = 2048; p.ldc = 2048;
    p.sCzHi = (long)2048 * 2048;  // partial plane stride (16 MiB)
    p.outScale = IWS;
    gemm_k<1, 0, 0, 0, 1, 2><<<dim3(16, 16, 2), 256, 0, stream>>>(p);
  }

  // ---- phase 5: fused x2-sum + rms + router; scan+assign ----
  rmsrouter_k<<<2048, 256, 0, stream>>>(x, wopart, wopart + (size_t)2048 * 2048,
                                        Wr, x2, xfh, idx2, g2, cnt);
  scan_k<<<1, 64, 0, stream>>>(cnt, offs, base);
  assign_k<<<8, 256, 0, stream>>>(idx2, base, perm, pos2);

  // ---- phase 6: MoE, horizontally fused (8 experts + shared as plane 8) ----
  tsplit_k<<<dim3(16, 64, 8), 256, 0, stream>>>(We1, WeT, (h16*)0, 2048, 512, WS, 0);
  tsplit_k<<<dim3(16, 64, 1), 256, 0, stream>>>(Ws1, WsPlane8, (h16*)0, 2048, 512, WS, 0);
  {
    GemmP p{};  // hcomb = relu(gather(xf) @ We1[z])^2, z=8 -> shared (identity)
    p.Ah = xfh; p.Bh = WeT; p.Ch = hcomb;
    p.N = 512; p.K = 2048; p.lda = 2048; p.ldb = 2048; p.ldc = 512;
    p.sBz = (long)512 * 2048; p.bzShift = 0;
    p.cnt = cnt; p.off = offs; p.perm = perm;
    p.outScale = IWS;
    gemm_k<0, 3, 1, 1, 2, 1><<<dim3(16, 4, 9), 256, 0, stream>>>(p);
  }
  tsplit_k<<<dim3(64, 16, 8), 256, 0, stream>>>(We2, WeT, (h16*)0, 512, 2048, WS, 0);
  tsplit_k<<<dim3(64, 16, 1), 256, 0, stream>>>(Ws2, WsPlane8, (h16*)0, 512, 2048, WS, 0);
  {
    GemmP p{};  // rpx = hcomb @ We2[z] (contiguous A rows, full async dbuf)
    p.Ah = hcomb; p.Bh = WeT; p.Ch = rpx;
    p.N = 2048; p.K = 512; p.lda = 512; p.ldb = 512; p.ldc = 2048;
    p.sBz = (long)2048 * 512; p.bzShift = 0;
    p.cnt = cnt; p.off = offs; p.perm = perm;
    p.outScale = IWS;
    gemm_k<0, 4, 1, 0, 1, 1><<<dim3(16, 16, 9), 256, 0, stream>>>(p);
  }

  // ---- phase 7: out = x2 + shared + gated routed ----
  combine_k<<<2048, 256, 0, stream>>>(x2, rpx, pos2, g2, out);
}